// Round 1
// baseline (1998.746 us; speedup 1.0000x reference)
//
#include <hip/hip_runtime.h>

// Switch-MoE  B=4,S=2048,D=2048,E=8,F=8192,C=512 on MI355X (gfx950)
// Pipeline: transpose+cast weights -> router -> capacity scan -> gather ->
//           GEMM1(bf16 MFMA, fused SiLU) -> GEMM2 -> combine.
// ws layout (bytes): w1t[0,256M) w2t[256M,512M) H[512M,768M) Xg/Y[768M,832M) + small arrays.

typedef unsigned short UST;
typedef short v8s __attribute__((ext_vector_type(8)));
typedef float v4f __attribute__((ext_vector_type(4)));

constexpr int Bb = 4, Ss = 2048, Dd = 2048, Ee = 8, Ff = 8192, Cap = 512;
constexpr int BS  = Bb * Ss;     // 8192 tokens
constexpr int RPE = Bb * Cap;    // 2048 rows per expert slab

__device__ __forceinline__ UST f2bf(float f) {
    union { float f; unsigned u; } v; v.f = f;
    unsigned r = v.u + 0x7fffu + ((v.u >> 16) & 1u);   // RNE
    return (UST)(r >> 16);
}
__device__ __forceinline__ float bf2f(UST u) {
    union { unsigned u; float f; } v; v.u = ((unsigned)u) << 16;
    return v.f;
}
__device__ __forceinline__ void load_lds16(const void* g, void* l) {
    __builtin_amdgcn_global_load_lds(
        (const __attribute__((address_space(1))) void*)g,
        (__attribute__((address_space(3))) void*)l, 16, 0, 0);
}

// ---------------- transpose + f32->bf16 cast:  in [E][R][Cc] f32 -> out [E][Cc][R] bf16
__global__ __launch_bounds__(256)
void transpose_cast(const float* __restrict__ in, UST* __restrict__ out, int R, int Cc) {
    __shared__ UST tile[64][65];
    const int e  = blockIdx.z;
    const int r0 = blockIdx.y * 64;
    const int c0 = blockIdx.x * 64;
    const float* src = in + (size_t)e * R * Cc;
    UST* dst = out + (size_t)e * R * Cc;
    const int tid = threadIdx.x;
#pragma unroll
    for (int it = 0; it < 4; it++) {
        int idx = it * 256 + tid;          // 0..1023
        int rr = idx >> 4;                 // 0..63
        int cc = (idx & 15) * 4;           // 0..60
        float4 v = *(const float4*)&src[(size_t)(r0 + rr) * Cc + c0 + cc];
        tile[rr][cc + 0] = f2bf(v.x); tile[rr][cc + 1] = f2bf(v.y);
        tile[rr][cc + 2] = f2bf(v.z); tile[rr][cc + 3] = f2bf(v.w);
    }
    __syncthreads();
#pragma unroll
    for (int it = 0; it < 4; it++) {
        int idx = it * 256 + tid;
        int cc = idx >> 4;                 // out row (input col) 0..63
        int rr = (idx & 15) * 4;           // out col (input row)
        ushort4 o;
        o.x = tile[rr + 0][cc]; o.y = tile[rr + 1][cc];
        o.z = tile[rr + 2][cc]; o.w = tile[rr + 3][cc];
        *(ushort4*)&dst[(size_t)(c0 + cc) * R + r0 + rr] = o;
    }
}

// ---------------- router: logits, argmax expert, top softmax prob. 1 wave / token.
__global__ __launch_bounds__(256)
void router(const float* __restrict__ x, const float* __restrict__ gw,
            float* __restrict__ logits, int* __restrict__ eidx, float* __restrict__ topp) {
    const int t    = blockIdx.x * 4 + (threadIdx.x >> 6);
    const int lane = threadIdx.x & 63;
    const float4* xr = (const float4*)(x + (size_t)t * Dd);
    const float4* g4 = (const float4*)gw;
    float acc[8] = {0,0,0,0,0,0,0,0};
#pragma unroll
    for (int i = 0; i < 8; i++) {
        float4 xv = xr[i * 64 + lane];
#pragma unroll
        for (int e = 0; e < 8; e++) {
            float4 gv = g4[e * 512 + i * 64 + lane];
            acc[e] += xv.x * gv.x + xv.y * gv.y + xv.z * gv.z + xv.w * gv.w;
        }
    }
#pragma unroll
    for (int e = 0; e < 8; e++)
        for (int off = 32; off > 0; off >>= 1)
            acc[e] += __shfl_xor(acc[e], off);
    if (lane == 0) {
        float mx = acc[0]; int mi = 0;
#pragma unroll
        for (int e = 1; e < 8; e++) if (acc[e] > mx) { mx = acc[e]; mi = e; }  // first-max tie
        float s = 0.f;
#pragma unroll
        for (int e = 0; e < 8; e++) s += __expf(acc[e] - mx);
#pragma unroll
        for (int e = 0; e < 8; e++) logits[(size_t)t * Ee + e] = acc[e];
        eidx[t] = mi;
        topp[t] = 1.f / s;
    }
}

// ---------------- capacity scan: exact cumsum-over-seq semantics. 1 block, wave b = batch b.
__global__ __launch_bounds__(256)
void scan_route(const int* __restrict__ eidx, int* __restrict__ slot_arr,
                int* __restrict__ row_of_token, int* __restrict__ token_of_row,
                int* __restrict__ ne, int* __restrict__ npad, float* __restrict__ ei_out) {
    __shared__ int cnt_be[Bb][Ee];
    __shared__ int base_be[Bb][Ee];
    const int lane = threadIdx.x & 63;
    const int b    = threadIdx.x >> 6;
    const unsigned long long lt = (1ull << lane) - 1ull;
    int cnt[8] = {0,0,0,0,0,0,0,0};
    for (int it = 0; it < 32; it++) {
        int t = b * Ss + it * 64 + lane;
        int e = eidx[t];
        int slot = -1;
#pragma unroll
        for (int ex = 0; ex < 8; ex++) {
            unsigned long long m = __ballot(e == ex);
            if (e == ex) slot = cnt[ex] + __popcll(m & lt);
            cnt[ex] += __popcll(m);
        }
        slot_arr[t] = slot;
    }
    if (lane == 0) {
#pragma unroll
        for (int e = 0; e < 8; e++) cnt_be[b][e] = cnt[e] < Cap ? cnt[e] : Cap;
    }
    __syncthreads();
    if (threadIdx.x < 8) {
        int e = threadIdx.x, base = 0;
        for (int bb = 0; bb < Bb; bb++) { base_be[bb][e] = base; base += cnt_be[bb][e]; }
        ne[e]   = base;
        npad[e] = (base + 127) & ~127;
    }
    __syncthreads();
    for (int it = 0; it < 32; it++) {
        int t = b * Ss + it * 64 + lane;
        int slot = slot_arr[t];
        int e = eidx[t];
        bool kept = slot < Cap;
        int row = kept ? (e * RPE + base_be[b][e] + slot) : -1;
        row_of_token[t] = row;
        if (kept) token_of_row[row] = t;
        ei_out[t] = kept ? (float)e : 0.0f;
    }
}

// ---------------- gather x rows (f32) -> compact bf16 slabs, zero the 128-pad rows
__global__ __launch_bounds__(256)
void gather_x(const float* __restrict__ x, const int* __restrict__ token_of_row,
              const int* __restrict__ ne, const int* __restrict__ npad, UST* __restrict__ Xg) {
    const int gr = blockIdx.x;             // 0..E*RPE-1
    const int e  = gr >> 11;
    const int r  = gr & (RPE - 1);
    const int n  = ne[e];
    UST* drow = Xg + (size_t)gr * Dd;
    const int tid = threadIdx.x;
    if (r < n) {
        const int t = token_of_row[gr];
        const float4* sx = (const float4*)(x + (size_t)t * Dd);
#pragma unroll
        for (int i = 0; i < 2; i++) {
            float4 v = sx[i * 256 + tid];
            ushort4 o; o.x = f2bf(v.x); o.y = f2bf(v.y); o.z = f2bf(v.z); o.w = f2bf(v.w);
            *(ushort4*)&drow[(i * 256 + tid) * 4] = o;
        }
    } else if (r < npad[e]) {
        ushort4 z; z.x = z.y = z.z = z.w = 0;
#pragma unroll
        for (int i = 0; i < 2; i++) *(ushort4*)&drow[(i * 256 + tid) * 4] = z;
    }
}

// ---------------- m97-style bf16 GEMM, C = A @ Bt^T, optional fused SiLU.
// A [E*RPE][K] bf16, Bt [E][N][K] bf16 (B transposed), C [E*RPE][N] bf16.
template <int K, int N, bool SILU>
__global__ __launch_bounds__(256)
void gemm_bt(const UST* __restrict__ A, const UST* __restrict__ Bt,
             UST* __restrict__ Cm, const int* __restrict__ npad) {
    const int e  = blockIdx.z;
    const int m0 = blockIdx.y * 128;
    if (m0 >= npad[e]) return;
    const int n0 = blockIdx.x * 128;

    __shared__ UST As[128 * 32];
    __shared__ UST Bs[128 * 32];

    const int tid  = threadIdx.x;
    const int lane = tid & 63;
    const int wid  = tid >> 6;
    const int r16  = lane >> 2;        // row within 16-row staging group
    const int kch  = lane & 3;         // 16B chunk within 64B k-stripe

    const UST* Ag = A  + ((size_t)(e * RPE + m0 + wid * 32 + r16)) * K + kch * 8;
    const UST* Bg = Bt + ((size_t)e * N + n0 + wid * 32 + r16) * K + kch * 8;
    UST* AsW = &As[(wid * 32) * 32];
    UST* BsW = &Bs[(wid * 32) * 32];

    v4f acc[4][4];
#pragma unroll
    for (int i = 0; i < 4; i++)
#pragma unroll
        for (int j = 0; j < 4; j++) acc[i][j] = (v4f)0.f;

    const int wm = (wid & 1) * 64, wn = (wid >> 1) * 64;
    const int l16 = lane & 15, quad = lane >> 4;
    const UST* AsR = &As[(wm + l16) * 32 + quad * 8];
    const UST* BsR = &Bs[(wn + l16) * 32 + quad * 8];

    for (int k0 = 0; k0 < K; k0 += 32) {
        __syncthreads();
        load_lds16(Ag + k0,                  AsW);
        load_lds16(Ag + (size_t)16 * K + k0, AsW + 16 * 32);
        load_lds16(Bg + k0,                  BsW);
        load_lds16(Bg + (size_t)16 * K + k0, BsW + 16 * 32);
        __syncthreads();
        v8s a[4], b[4];
#pragma unroll
        for (int i = 0; i < 4; i++) a[i] = *(const v8s*)(AsR + i * 16 * 32);
#pragma unroll
        for (int j = 0; j < 4; j++) b[j] = *(const v8s*)(BsR + j * 16 * 32);
#pragma unroll
        for (int i = 0; i < 4; i++)
#pragma unroll
            for (int j = 0; j < 4; j++)
                acc[i][j] = __builtin_amdgcn_mfma_f32_16x16x32_bf16(a[i], b[j], acc[i][j], 0, 0, 0);
    }

#pragma unroll
    for (int i = 0; i < 4; i++) {
#pragma unroll
        for (int r = 0; r < 4; r++) {
            const int row = e * RPE + m0 + wm + i * 16 + quad * 4 + r;
            UST* crow = Cm + (size_t)row * N + n0 + wn + l16;
#pragma unroll
            for (int j = 0; j < 4; j++) {
                float v = acc[i][j][r];
                if (SILU) v = v / (1.f + __expf(-v));
                crow[j * 16] = f2bf(v);
            }
        }
    }
}

// ---------------- combine: hidden = top_prob * (routed ? Y_row : x_row)
__global__ __launch_bounds__(256)
void combine(const float* __restrict__ x, const UST* __restrict__ Y,
             const int* __restrict__ row_of_token, const float* __restrict__ topp,
             float* __restrict__ out) {
    const int t = blockIdx.x;
    const float p = topp[t];
    const int row = row_of_token[t];
    float* orow = out + (size_t)t * Dd;
    const int tid = threadIdx.x;
    if (row >= 0) {
        const ushort4* yr = (const ushort4*)(Y + (size_t)row * Dd);
#pragma unroll
        for (int i = 0; i < 2; i++) {
            ushort4 v = yr[i * 256 + tid];
            float4 o; o.x = p * bf2f(v.x); o.y = p * bf2f(v.y);
            o.z = p * bf2f(v.z); o.w = p * bf2f(v.w);
            *(float4*)&orow[(i * 256 + tid) * 4] = o;
        }
    } else {
        const float4* xr = (const float4*)(x + (size_t)t * Dd);
#pragma unroll
        for (int i = 0; i < 2; i++) {
            float4 v = xr[i * 256 + tid];
            float4 o; o.x = p * v.x; o.y = p * v.y; o.z = p * v.z; o.w = p * v.w;
            *(float4*)&orow[(i * 256 + tid) * 4] = o;
        }
    }
}

extern "C" void kernel_launch(void* const* d_in, const int* in_sizes, int n_in,
                              void* d_out, int out_size, void* d_ws, size_t ws_size,
                              hipStream_t stream) {
    const float* x  = (const float*)d_in[0];
    const float* gw = (const float*)d_in[1];
    const float* w1 = (const float*)d_in[2];
    const float* w2 = (const float*)d_in[3];

    float* out_hidden = (float*)d_out;
    float* out_logits = out_hidden + (size_t)BS * Dd;
    float* out_ei     = out_logits + (size_t)BS * Ee;

    constexpr size_t SZ_WT = (size_t)Ee * Ff * Dd * 2;   // 256 MiB
    char* ws = (char*)d_ws;
    UST* w1t = (UST*)(ws);                               // [E][F][D] bf16
    UST* w2t = (UST*)(ws + SZ_WT);                       // [E][D][F] bf16
    UST* H   = (UST*)(ws + 2 * SZ_WT);                   // [E*RPE][F] bf16
    UST* Xg  = (UST*)(ws + 3 * SZ_WT);                   // [E*RPE][D] bf16 (Y aliases: Xg dead after GEMM1)
    UST* Y   = Xg;
    char* p = ws + 3 * SZ_WT + (size_t)Ee * RPE * Dd * 2;
    int*   eidx         = (int*)p;    p += BS * 4;
    float* topp         = (float*)p;  p += BS * 4;
    int*   slot_arr     = (int*)p;    p += BS * 4;
    int*   row_of_token = (int*)p;    p += BS * 4;
    int*   token_of_row = (int*)p;    p += Ee * RPE * 4;
    int*   ne_d         = (int*)p;    p += 32;
    int*   npad_d       = (int*)p;    p += 32;

    transpose_cast<<<dim3(Ff / 64, Dd / 64, Ee), 256, 0, stream>>>(w1, w1t, Dd, Ff);
    transpose_cast<<<dim3(Dd / 64, Ff / 64, Ee), 256, 0, stream>>>(w2, w2t, Ff, Dd);
    router<<<dim3(BS / 4), 256, 0, stream>>>(x, gw, out_logits, eidx, topp);
    scan_route<<<dim3(1), 256, 0, stream>>>(eidx, slot_arr, row_of_token, token_of_row,
                                            ne_d, npad_d, out_ei);
    gather_x<<<dim3(Ee * RPE), 256, 0, stream>>>(x, token_of_row, ne_d, npad_d, Xg);
    gemm_bt<Dd, Ff, true ><<<dim3(Ff / 128, RPE / 128, Ee), 256, 0, stream>>>(Xg, w1t, H, npad_d);
    gemm_bt<Ff, Dd, false><<<dim3(Dd / 128, RPE / 128, Ee), 256, 0, stream>>>(H, w2t, Y, npad_d);
    combine<<<dim3(BS), 256, 0, stream>>>(x, Y, row_of_token, topp, out_hidden);
}